// Round 13
// baseline (1311.554 us; speedup 1.0000x reference)
//
#include <hip/hip_runtime.h>

#define PI_F 3.14159265358979323846f

#define NCH   1000
#define NPTS  30000
#define NHALF 15000      // NPTS/2 packed complex samples
#define NFFT  32768      // complex FFT length (real length 65536)
#define NBF32 1024       // butterflies per channel per radix-32 pass (NFFT/32)
#define STR   32770      // per-channel stride in complex elements
#define GSTR  32770      // per-channel stride of the gain array (floats); needs 32769
#define XCOR  59999

#define UC 0.99518472667219693f
#define US 0.09801714032956060f

__device__ __forceinline__ float2 cadd(float2 a, float2 b){ return make_float2(a.x+b.x, a.y+b.y); }
__device__ __forceinline__ float2 csub(float2 a, float2 b){ return make_float2(a.x-b.x, a.y-b.y); }
__device__ __forceinline__ float2 cmul(float2 a, float2 b){ return make_float2(a.x*b.x - a.y*b.y, a.x*b.y + a.y*b.x); }
__device__ __forceinline__ float2 conjmul(float2 a, float2 b){  // conj(a)*b
  return make_float2(a.x*b.x + a.y*b.y, a.x*b.y - a.y*b.x);
}

template<int S>
__device__ __forceinline__ float2 mulIs(float2 z){ return make_float2(-(float)S*z.y, (float)S*z.x); }

// 8-point DFT, ω = e^{S*2πi/8}
template<int S>
__device__ __forceinline__ void dft8(float2 v[8]){
  const float r2 = 0.7071067811865476f;
  const float sf = (float)S;
  float2 ea=cadd(v[0],v[4]), eb=csub(v[0],v[4]);
  float2 ec=cadd(v[2],v[6]), ed=csub(v[2],v[6]);
  float2 oa=cadd(v[1],v[5]), ob=csub(v[1],v[5]);
  float2 oc=cadd(v[3],v[7]), od=csub(v[3],v[7]);
  float2 ied=mulIs<S>(ed), iod=mulIs<S>(od);
  float2 E0=cadd(ea,ec), E2=csub(ea,ec), E1=cadd(eb,ied), E3=csub(eb,ied);
  float2 O0=cadd(oa,oc), O2=csub(oa,oc), O1=cadd(ob,iod), O3=csub(ob,iod);
  float2 T1 = make_float2(r2*(O1.x - sf*O1.y), r2*(O1.y + sf*O1.x));
  float2 T2 = mulIs<S>(O2);
  float2 T3 = make_float2(r2*(-O3.x - sf*O3.y), r2*(sf*O3.x - O3.y));
  v[0]=cadd(E0,O0); v[4]=csub(E0,O0);
  v[1]=cadd(E1,T1); v[5]=csub(E1,T1);
  v[2]=cadd(E2,T2); v[6]=csub(E2,T2);
  v[3]=cadd(E3,T3); v[7]=csub(E3,T3);
}

template<int S>
__device__ __forceinline__ void dft4(float2 v[4]){
  float2 t0=cadd(v[0],v[2]), t1=csub(v[0],v[2]);
  float2 t2=cadd(v[1],v[3]), t3=mulIs<S>(csub(v[1],v[3]));
  v[0]=cadd(t0,t2); v[2]=csub(t0,t2);
  v[1]=cadd(t1,t3); v[3]=csub(t1,t3);
}

// 32-point DFT in registers
template<int S>
__device__ __forceinline__ void dft32(float2 v[32]){
  constexpr float TC[22] = {
    1.f, 0.98078528040323044f, 0.92387953251128674f, 0.83146961230254524f,
    0.70710678118654757f, 0.55557023301960218f, 0.38268343236508978f, 0.19509032201612825f,
    0.f, -0.19509032201612825f, -0.38268343236508978f, -0.55557023301960218f,
    -0.70710678118654757f, -0.83146961230254524f, -0.92387953251128674f, -0.98078528040323044f,
    -1.f, -0.98078528040323044f, -0.92387953251128674f, -0.83146961230254524f,
    -0.70710678118654757f, -0.55557023301960218f };
  constexpr float TS[22] = {
    0.f, 0.19509032201612825f, 0.38268343236508978f, 0.55557023301960218f,
    0.70710678118654757f, 0.83146961230254524f, 0.92387953251128674f, 0.98078528040323044f,
    1.f, 0.98078528040323044f, 0.92387953251128674f, 0.83146961230254524f,
    0.70710678118654757f, 0.55557023301960218f, 0.38268343236508978f, 0.19509032201612825f,
    0.f, -0.19509032201612825f, -0.38268343236508978f, -0.55557023301960218f,
    -0.70710678118654757f, -0.83146961230254524f };
  float2 y[4][8];
  #pragma unroll
  for (int b = 0; b < 4; ++b)
    #pragma unroll
    for (int a = 0; a < 8; ++a) y[b][a] = v[4*a + b];
  #pragma unroll
  for (int b = 0; b < 4; ++b) dft8<S>(y[b]);
  #pragma unroll
  for (int b = 1; b < 4; ++b)
    #pragma unroll
    for (int k1 = 1; k1 < 8; ++k1) {
      int m = b*k1;
      float2 w = make_float2(TC[m], (float)S * TS[m]);
      y[b][k1] = cmul(y[b][k1], w);
    }
  #pragma unroll
  for (int k1 = 0; k1 < 8; ++k1) {
    float2 z[4] = { y[0][k1], y[1][k1], y[2][k1], y[3][k1] };
    dft4<S>(z);
    #pragma unroll
    for (int k2 = 0; k2 < 4; ++k2) v[k1 + 8*k2] = z[k2];
  }
}

template<int S>
__device__ __forceinline__ void stage_twiddle32(float2 v[32], float ang){
  float s1,c1,s8,c8;
  __sincosf(ang, &s1, &c1);
  __sincosf(8.f*ang, &s8, &c8);
  float2 w1 = make_float2(c1, s1), w8 = make_float2(c8, s8);
  float2 w16 = cmul(w8, w8), w24 = cmul(w16, w8);
  float2 base[4] = { make_float2(1.f, 0.f), w8, w16, w24 };
  #pragma unroll
  for (int m = 0; m < 4; ++m) {
    float2 wr = base[m];
    if (m > 0) v[8*m] = cmul(v[8*m], wr);
    #pragma unroll
    for (int l = 1; l < 8; ++l) { wr = cmul(wr, w1); v[8*m+l] = cmul(v[8*m+l], wr); }
  }
}

// ========== FWD FUSED: stages LG0 + LG5 through LDS (verified round 7) ==========
__global__ __launch_bounds__(256) void fft_fwd_fused(const float* __restrict__ d1, const float* __restrict__ d2,
                                                     float2* __restrict__ out, int cb, int ch0)
{
  __shared__ float2 lds[256*33];   // 67.6 KB, stride-33 rows
  const int bid = blockIdx.x;
  const int c = bid >> 2, b = bid & 3;
  const int t = threadIdx.x;
  const float* src = (c < cb) ? (d1 + (size_t)(ch0 + c) * NPTS)
                              : (d2 + (size_t)(ch0 + c - cb) * NPTS);
  const float2* src2 = reinterpret_cast<const float2*>(src);

  const int j1 = 8*b + (t & 7) + 32*(t >> 3);
  float2 v[32];
  #pragma unroll
  for (int r = 0; r < 32; ++r) {
    int m = j1 + (r << 10);
    v[r] = (m < NHALF) ? src2[m] : make_float2(0.f, 0.f);
  }
  dft32<-1>(v);
  #pragma unroll
  for (int r = 0; r < 32; ++r) lds[t*33 + r] = v[r];
  __syncthreads();

  const int d = t >> 5, jm = t & 31;
  #pragma unroll
  for (int r = 0; r < 32; ++r) v[r] = lds[(d + 8*r)*33 + jm];
  stage_twiddle32<-1>(v, -(2.0f*PI_F) * (float)jm * (1.0f/1024.0f));
  dft32<-1>(v);
  const int j2 = 256*b + t;
  float2* dst = out + (size_t)c * STR + ((j2 >> 5) << 10) + jm;
  #pragma unroll
  for (int r = 0; r < 32; ++r) dst[(size_t)(r << 5)] = v[r];
}

// ---------- generic Stockham radix-32 pass, Ns = 2^LG ----------
template<int LG, int S>
__global__ __launch_bounds__(256) void fft_pass32(const float2* __restrict__ in, float2* __restrict__ out)
{
  int tid = blockIdx.x*256 + threadIdx.x;
  int c = tid >> 10;
  int j = tid & (NBF32-1);
  const float2* src = in + (size_t)c * STR;
  float2 v[32];
  #pragma unroll
  for (int r = 0; r < 32; ++r) v[r] = src[j + (r << 10)];
  constexpr int NS = 1 << LG;
  int jm = j & (NS - 1);
  if constexpr (LG > 0) {
    float ang = (float)S * (2.0f*PI_F) * (float)jm / (float)(NS*32);
    stage_twiddle32<S>(v, ang);
  }
  dft32<S>(v);
  int idxD = ((j >> LG) << (LG+5)) + jm;
  float2* dst = out + (size_t)c * STR + idxD;
  #pragma unroll
  for (int r = 0; r < 32; ++r) dst[(size_t)(r << LG)] = v[r];
}

// ---------- WHITEN_SCAN: unpack (transient) -> mags -> scan -> GAIN array (no W materialized) ----------
__device__ __forceinline__ int padidx(int m){ return m + (m >> 5); }

__global__ __launch_bounds__(1024) void whiten_scan(const float2* __restrict__ zbuf,
                                                    float* __restrict__ gbase)
{
  const int ch = blockIdx.x;
  const int t  = threadIdx.x;
  const float2* Z = zbuf + (size_t)ch * STR;
  float* G = gbase + (size_t)ch * GSTR;
  __shared__ float s[33793];     // 32769 magnitudes, padded every 32
  __shared__ float wsums[16];

  // phase 1: unpack X[k] transiently; mags to LDS. w(k)=e^{-i pi k/32768} via recurrence.
  {
    float s0, c0; __sincosf(-PI_F*(float)t*(1.0f/32768.0f), &s0, &c0);
    float2 uw = make_float2(c0, s0);
    const float2 uwstep = make_float2(UC, -US);
    #pragma unroll
    for (int i = 0; i < 33; ++i) {
      int k = i*1024 + t;
      if (i < 32 || t == 0) {
        float2 zk = Z[k & (NFFT-1)];
        float2 zn = Z[(NFFT - k) & (NFFT-1)];
        float2 xe = make_float2(0.5f*(zk.x+zn.x), 0.5f*(zk.y-zn.y));
        float2 xh = make_float2(0.5f*(zk.x-zn.x), 0.5f*(zk.y+zn.y));
        float2 xo = make_float2(xh.y, -xh.x);
        float2 Xi = cadd(xe, cmul(uw, xo));
        s[padidx(k)] = sqrtf(Xi.x*Xi.x + Xi.y*Xi.y);
      }
      uw = cmul(uw, uwstep);
    }
  }
  __syncthreads();

  // phase 2: block-wide inclusive cumsum of magnitudes (in place in LDS)
  const int base = t*32;
  float sum = 0.f;
  #pragma unroll
  for (int q = 0; q < 32; ++q) sum += s[padidx(base+q)];
  if (t == 1023) sum += s[padidx(32768)];
  const int lane = t & 63, wid = t >> 6;
  float v = sum;
  #pragma unroll
  for (int off = 1; off < 64; off <<= 1) {
    float u = __shfl_up(v, off);
    if (lane >= off) v += u;
  }
  if (lane == 63) wsums[wid] = v;
  __syncthreads();
  float wexcl = 0.f;
  for (int w = 0; w < 16; ++w) wexcl += (w < wid) ? wsums[w] : 0.f;
  float run = wexcl + (v - sum);
  #pragma unroll
  for (int q = 0; q < 32; ++q) {
    int idx = padidx(base+q);
    run += s[idx];
    s[idx] = run;
  }
  if (t == 1023) { int idx = padidx(32768); run += s[idx]; s[idx] = run; }
  __syncthreads();

  // phase 3: gain g[k] = taper / smoothed (0 if smoothed<=0); hi-taper via recurrence
  const float a0 = s[padidx(0)];
  const float alast = s[padidx(32768)] - s[padidx(32767)];
  {
    float su, cu; __sincosf(((float)t - 13108.0f)*(PI_F/39320.0f), &su, &cu);
    float2 tu = make_float2(cu, su);
    float tss, tcc; __sincosf(1024.0f*(PI_F/39320.0f), &tss, &tcc);
    const float2 tustep = make_float2(tcc, tss);
    #pragma unroll
    for (int i = 0; i < 33; ++i) {
      int k = i*1024 + t;
      if (i < 32 || t == 0) {
        int hi = k + 327; if (hi > 32768) hi = 32768;
        int lom1 = k - 328;
        float Shi = s[padidx(hi)];
        float Slo = (lom1 >= 0) ? s[padidx(lom1)] : 0.f;
        float lc = (k < 327) ? (float)(327 - k) : 0.f;
        float rc = (k > 32441) ? (float)(k - 32441) : 0.f;
        float smoothed = (lc*a0 + (Shi - Slo) + rc*alast) * (1.0f/655.0f);
        float tp = 1.0f;
        if (k < 131)        { float sn = __sinf((float)k * (PI_F/260.0f)); tp = sn*sn; }
        else if (k >= 13108) tp = tu.x*tu.x;
        G[k] = (smoothed > 0.f) ? tp / smoothed : 0.f;
      }
      tu = cmul(tu, tustep);
    }
  }
}

// ================= CROSS_INV0_PAIR_V2: unpack (recompute) + gains + cross + pack + inv stage-0 =================
__device__ __forceinline__ float2 pack_zinv(float2 Ck, float2 Cm, float2 pw){
  const float scale = 1.0f/32768.0f;
  float2 xe = make_float2(0.5f*(Ck.x+Cm.x), 0.5f*(Ck.y-Cm.y));
  float2 d  = make_float2(0.5f*(Ck.x-Cm.x), 0.5f*(Ck.y+Cm.y));
  float2 xo = cmul(pw, d);
  return make_float2((xe.x - xo.y)*scale, (xe.y + xo.x)*scale);
}

// X[k], X[32768-k] from Z[k], Z[32768-k] with u = e^{-i pi k/32768} (round-6 verified)
__device__ __forceinline__ void unpack_w(float2 zk, float2 zm, float2 u, float2& Xn, float2& Xm){
  float2 xe = make_float2(0.5f*(zk.x+zm.x), 0.5f*(zk.y-zm.y));
  float2 xh = make_float2(0.5f*(zk.x-zm.x), 0.5f*(zk.y+zm.y));
  float2 xo = make_float2(xh.y, -xh.x);
  float2 pr = cmul(u, xo);
  Xn = make_float2(xe.x+pr.x, xe.y+pr.y);
  Xm = make_float2(xe.x-pr.x, -(xe.y-pr.y));
}

__global__ __launch_bounds__(256) void cross_inv0_pair_v2(const float2* __restrict__ Zb,
                                                          const float* __restrict__ gbase,
                                                          float2* __restrict__ out0, int cb)
{
  __shared__ float2 zbs[256*33];   // 67.6 KB zB stash (stride 33)
  const int bid = blockIdx.x;
  const int c = bid >> 1;
  const int t = threadIdx.x;
  const int p = ((bid & 1) << 8) + t;      // pair index 0..511
  const float2* Z1 = Zb + (size_t)c * STR;
  const float2* Z2 = Zb + (size_t)(cb + c) * STR;
  const float* G1 = gbase + (size_t)c * GSTR;
  const float* G2 = gbase + (size_t)(cb + c) * GSTR;
  const float scale = 1.0f/32768.0f;
  float2 zA[32];
  float2* zB = zbs + t*33;

  if (p != 0) {
    float su, cu; __sincosf(-PI_F*(float)p*(1.0f/32768.0f), &su, &cu);
    float2 u = make_float2(cu, su);                 // e^{-i pi m/32768}, m = p+1024r
    const float2 ustep = make_float2(UC, -US);
    #pragma unroll
    for (int r = 0; r < 32; ++r) {
      int m  = p + (r << 10);
      int mm = 32768 - m;
      float2 X1n, X1m, X2n, X2m;
      unpack_w(Z1[m], Z1[mm], u, X1n, X1m);
      unpack_w(Z2[m], Z2[mm], u, X2n, X2m);
      float g1m = G1[m], g1mm = G1[mm], g2m = G2[m], g2mm = G2[mm];
      float2 W1m  = make_float2(X1n.x*g1m,  X1n.y*g1m);
      float2 W1mm = make_float2(X1m.x*g1mm, X1m.y*g1mm);
      float2 W2m  = make_float2(X2n.x*g2m,  X2n.y*g2m);
      float2 W2mm = make_float2(X2m.x*g2mm, X2m.y*g2mm);
      float2 Ck = conjmul(W1m,  W2m);
      float2 Cm = conjmul(W1mm, W2mm);
      float2 pw = make_float2(u.x, -u.y);           // e^{+i pi m/32768}
      zA[r]    = pack_zinv(Ck, Cm, pw);
      zB[31-r] = pack_zinv(Cm, Ck, make_float2(-pw.x, pw.y));
      u = cmul(u, ustep);
    }
  } else {
    // ---- comb 0 (zA): pairs (i, 32-i); specials bins 0/32768, 16384 ----
    {
      float2 z0 = Z1[0], y0 = Z2[0];
      float2 X1n = make_float2(z0.x + z0.y, 0.f), X1m = make_float2(z0.x - z0.y, 0.f);
      float2 X2n = make_float2(y0.x + y0.y, 0.f), X2m = make_float2(y0.x - y0.y, 0.f);
      float2 W10 = make_float2(X1n.x*G1[0], 0.f),     W20 = make_float2(X2n.x*G2[0], 0.f);
      float2 W1N = make_float2(X1m.x*G1[32768], 0.f), W2N = make_float2(X2m.x*G2[32768], 0.f);
      float2 Ck = conjmul(W10, W20);
      float2 Cm = conjmul(W1N, W2N);
      zA[0] = pack_zinv(Ck, Cm, make_float2(1.f, 0.f));
    }
    #pragma unroll
    for (int i = 1; i < 16; ++i) {
      int m = i << 10, mm = 32768 - m;
      float su, cu; __sincosf(-PI_F*(float)m*(1.0f/32768.0f), &su, &cu);
      float2 u = make_float2(cu, su);
      float2 X1n, X1m, X2n, X2m;
      unpack_w(Z1[m], Z1[mm], u, X1n, X1m);
      unpack_w(Z2[m], Z2[mm], u, X2n, X2m);
      float g1m = G1[m], g1mm = G1[mm], g2m = G2[m], g2mm = G2[mm];
      float2 W1m  = make_float2(X1n.x*g1m,  X1n.y*g1m);
      float2 W1mm = make_float2(X1m.x*g1mm, X1m.y*g1mm);
      float2 W2m  = make_float2(X2n.x*g2m,  X2n.y*g2m);
      float2 W2mm = make_float2(X2m.x*g2mm, X2m.y*g2mm);
      float2 Ck = conjmul(W1m,  W2m);
      float2 Cm = conjmul(W1mm, W2mm);
      float2 pw = make_float2(u.x, -u.y);
      zA[i]    = pack_zinv(Ck, Cm, pw);
      zA[32-i] = pack_zinv(Cm, Ck, make_float2(-pw.x, pw.y));
    }
    {
      float2 z16 = Z1[16384], y16 = Z2[16384];
      float2 X1 = make_float2(z16.x, -z16.y), X2 = make_float2(y16.x, -y16.y);
      float g1 = G1[16384], g2 = G2[16384];
      float2 W1 = make_float2(X1.x*g1, X1.y*g1), W2 = make_float2(X2.x*g2, X2.y*g2);
      float2 C16 = conjmul(W1, W2);
      zA[16] = make_float2(C16.x*scale, -C16.y*scale);  // Zinv[16384] = conj(C)/N
    }
    // ---- comb 512 (zB): pairs (i, 31-i) ----
    #pragma unroll
    for (int i = 0; i < 16; ++i) {
      int m = (i << 10) + 512, mm = 32768 - m;
      float su, cu; __sincosf(-PI_F*(float)m*(1.0f/32768.0f), &su, &cu);
      float2 u = make_float2(cu, su);
      float2 X1n, X1m, X2n, X2m;
      unpack_w(Z1[m], Z1[mm], u, X1n, X1m);
      unpack_w(Z2[m], Z2[mm], u, X2n, X2m);
      float g1m = G1[m], g1mm = G1[mm], g2m = G2[m], g2mm = G2[mm];
      float2 W1m  = make_float2(X1n.x*g1m,  X1n.y*g1m);
      float2 W1mm = make_float2(X1m.x*g1mm, X1m.y*g1mm);
      float2 W2m  = make_float2(X2n.x*g2m,  X2n.y*g2m);
      float2 W2mm = make_float2(X2m.x*g2mm, X2m.y*g2mm);
      float2 Ck = conjmul(W1m,  W2m);
      float2 Cm = conjmul(W1mm, W2mm);
      float2 pw = make_float2(u.x, -u.y);
      zB[i]    = pack_zinv(Ck, Cm, pw);
      zB[31-i] = pack_zinv(Cm, Ck, make_float2(-pw.x, pw.y));
    }
  }

  // stage-0 inverse for comb p
  dft32<1>(zA);
  {
    float4* o4 = reinterpret_cast<float4*>(out0 + (size_t)c*STR + (size_t)p*32);
    #pragma unroll
    for (int r = 0; r < 32; r += 2)
      o4[r>>1] = make_float4(zA[r].x, zA[r].y, zA[r+1].x, zA[r+1].y);
  }
  // stage-0 inverse for comb q (reload from stash; thread-private)
  {
    float2 zq[32];
    #pragma unroll
    for (int r = 0; r < 32; ++r) zq[r] = zB[r];
    dft32<1>(zq);
    const int jout = (p == 0) ? 512 : (1024 - p);
    float4* o4 = reinterpret_cast<float4*>(out0 + (size_t)c*STR + (size_t)jout*32);
    #pragma unroll
    for (int r = 0; r < 32; r += 2)
      o4[r>>1] = make_float4(zq[r].x, zq[r].y, zq[r+1].x, zq[r+1].y);
  }
}

// ---------- inverse final pass (Ns=1024, radix-32), fused unpack + roll + slice (verified r7) ----------
__global__ __launch_bounds__(256) void fft_inv_final32(const float2* __restrict__ in, float* __restrict__ out, int ch0)
{
  int tid = blockIdx.x*256 + threadIdx.x;
  int c = tid >> 10;
  int j = tid & (NBF32-1);
  const float2* src = in + (size_t)c * STR;
  float2 v[32];
  #pragma unroll
  for (int r = 0; r < 32; ++r) v[r] = src[j + (r << 10)];
  float ang = (2.0f*PI_F) * (float)j * (1.0f/32768.0f);
  stage_twiddle32<1>(v, ang);
  dft32<1>(v);
  float* o = out + (size_t)(ch0 + c) * XCOR;
  #pragma unroll
  for (int r = 0; r < 32; ++r) {
    int n = j + (r << 10);
    int m = 2*n;
    int j1 = (m <= 29999) ? (m + 29999) : ((m >= 35537) ? (m - 35537) : -1);
    if (j1 >= 0) o[j1] = v[r].x;
    int m2 = m + 1;
    int j2 = (m2 <= 29999) ? (m2 + 29999) : ((m2 >= 35537) ? (m2 - 35537) : -1);
    if (j2 >= 0) o[j2] = v[r].y;
  }
}

__global__ void diag_kernel(float* out, float vv){ if (threadIdx.x==0 && blockIdx.x==0) out[0] = vv; }

extern "C" void kernel_launch(void* const* d_in, const int* in_sizes, int n_in,
                              void* d_out, int out_size, void* d_ws, size_t ws_size,
                              hipStream_t stream)
{
  const float* d1 = (const float*)d_in[0];
  const float* d2 = (const float*)d_in[1];
  float* out = (float*)d_out;

  const size_t bytesPerCh = 2ULL * 2ULL * (size_t)STR * sizeof(float2);
  int CB = (int)(ws_size / bytesPerCh);
  if (CB > NCH) CB = NCH;
  if (CB < 1) { diag_kernel<<<1,1,0,stream>>>(out, (float)ws_size); return; }

  float2* bufA = (float2*)d_ws;
  float2* bufB = bufA + (size_t)2 * CB * STR;
  float*  gbase = (float*)bufA;                     // 2*CB channels x GSTR floats = CB*STR float2
  float2* out0  = bufA + (size_t)CB * STR;          // stage-0 output region (CB channels)

  for (int ch0 = 0; ch0 < NCH; ch0 += CB) {
    int cb = (NCH - ch0 < CB) ? (NCH - ch0) : CB;
    int nch2 = 2*cb;
    dim3 thr(256);

    // forward: fused stages LG0+LG5 (inputs -> A), then LG10 -> natural-order Z (A -> B)
    fft_fwd_fused      <<<dim3(nch2*4), thr, 0, stream>>>(d1, d2, bufA, cb, ch0);
    fft_pass32<10,-1>  <<<dim3(nch2*4), thr, 0, stream>>>(bufA, bufB);

    // whiten -> scalar gain arrays (reads B, writes G; Z in B preserved)
    whiten_scan        <<<dim3(nch2), dim3(1024), 0, stream>>>(bufB, gbase);

    // unpack(recompute) + gains + cross + irfft pack + inverse stage-0: B,G -> out0
    cross_inv0_pair_v2 <<<dim3(cb*2), thr, 0, stream>>>(bufB, gbase, out0, cb);

    // inverse: middle pass LG=5 (out0 -> B), final LG=10 fused with roll + slice (B -> out)
    fft_pass32<5,1>    <<<dim3(cb*4), thr, 0, stream>>>(out0, bufB);
    fft_inv_final32    <<<dim3(cb*4), thr, 0, stream>>>(bufB, out, ch0);
  }
}

// Round 14
// 1180.984 us; speedup vs baseline: 1.1106x; 1.1106x over previous
//
#include <hip/hip_runtime.h>

#define PI_F 3.14159265358979323846f

#define NCH   1000
#define NPTS  30000
#define NHALF 15000      // NPTS/2 packed complex samples
#define NFFT  32768      // complex FFT length (real length 65536)
#define NBF32 1024       // butterflies per channel per radix-32 pass (NFFT/32)
#define STR   32770      // per-channel stride in complex elements
#define XCOR  59999

#define UC 0.99518472667219693f
#define US 0.09801714032956060f

__device__ __forceinline__ float2 cadd(float2 a, float2 b){ return make_float2(a.x+b.x, a.y+b.y); }
__device__ __forceinline__ float2 csub(float2 a, float2 b){ return make_float2(a.x-b.x, a.y-b.y); }
__device__ __forceinline__ float2 cmul(float2 a, float2 b){ return make_float2(a.x*b.x - a.y*b.y, a.x*b.y + a.y*b.x); }
__device__ __forceinline__ float2 conjmul(float2 a, float2 b){  // conj(a)*b
  return make_float2(a.x*b.x + a.y*b.y, a.x*b.y - a.y*b.x);
}

template<int S>
__device__ __forceinline__ float2 mulIs(float2 z){ return make_float2(-(float)S*z.y, (float)S*z.x); }

// 8-point DFT, ω = e^{S*2πi/8}
template<int S>
__device__ __forceinline__ void dft8(float2 v[8]){
  const float r2 = 0.7071067811865476f;
  const float sf = (float)S;
  float2 ea=cadd(v[0],v[4]), eb=csub(v[0],v[4]);
  float2 ec=cadd(v[2],v[6]), ed=csub(v[2],v[6]);
  float2 oa=cadd(v[1],v[5]), ob=csub(v[1],v[5]);
  float2 oc=cadd(v[3],v[7]), od=csub(v[3],v[7]);
  float2 ied=mulIs<S>(ed), iod=mulIs<S>(od);
  float2 E0=cadd(ea,ec), E2=csub(ea,ec), E1=cadd(eb,ied), E3=csub(eb,ied);
  float2 O0=cadd(oa,oc), O2=csub(oa,oc), O1=cadd(ob,iod), O3=csub(ob,iod);
  float2 T1 = make_float2(r2*(O1.x - sf*O1.y), r2*(O1.y + sf*O1.x));
  float2 T2 = mulIs<S>(O2);
  float2 T3 = make_float2(r2*(-O3.x - sf*O3.y), r2*(sf*O3.x - O3.y));
  v[0]=cadd(E0,O0); v[4]=csub(E0,O0);
  v[1]=cadd(E1,T1); v[5]=csub(E1,T1);
  v[2]=cadd(E2,T2); v[6]=csub(E2,T2);
  v[3]=cadd(E3,T3); v[7]=csub(E3,T3);
}

template<int S>
__device__ __forceinline__ void dft4(float2 v[4]){
  float2 t0=cadd(v[0],v[2]), t1=csub(v[0],v[2]);
  float2 t2=cadd(v[1],v[3]), t3=mulIs<S>(csub(v[1],v[3]));
  v[0]=cadd(t0,t2); v[2]=csub(t0,t2);
  v[1]=cadd(t1,t3); v[3]=csub(t1,t3);
}

// 32-point DFT in registers
template<int S>
__device__ __forceinline__ void dft32(float2 v[32]){
  constexpr float TC[22] = {
    1.f, 0.98078528040323044f, 0.92387953251128674f, 0.83146961230254524f,
    0.70710678118654757f, 0.55557023301960218f, 0.38268343236508978f, 0.19509032201612825f,
    0.f, -0.19509032201612825f, -0.38268343236508978f, -0.55557023301960218f,
    -0.70710678118654757f, -0.83146961230254524f, -0.92387953251128674f, -0.98078528040323044f,
    -1.f, -0.98078528040323044f, -0.92387953251128674f, -0.83146961230254524f,
    -0.70710678118654757f, -0.55557023301960218f };
  constexpr float TS[22] = {
    0.f, 0.19509032201612825f, 0.38268343236508978f, 0.55557023301960218f,
    0.70710678118654757f, 0.83146961230254524f, 0.92387953251128674f, 0.98078528040323044f,
    1.f, 0.98078528040323044f, 0.92387953251128674f, 0.83146961230254524f,
    0.70710678118654757f, 0.55557023301960218f, 0.38268343236508978f, 0.19509032201612825f,
    0.f, -0.19509032201612825f, -0.38268343236508978f, -0.55557023301960218f,
    -0.70710678118654757f, -0.83146961230254524f };
  float2 y[4][8];
  #pragma unroll
  for (int b = 0; b < 4; ++b)
    #pragma unroll
    for (int a = 0; a < 8; ++a) y[b][a] = v[4*a + b];
  #pragma unroll
  for (int b = 0; b < 4; ++b) dft8<S>(y[b]);
  #pragma unroll
  for (int b = 1; b < 4; ++b)
    #pragma unroll
    for (int k1 = 1; k1 < 8; ++k1) {
      int m = b*k1;
      float2 w = make_float2(TC[m], (float)S * TS[m]);
      y[b][k1] = cmul(y[b][k1], w);
    }
  #pragma unroll
  for (int k1 = 0; k1 < 8; ++k1) {
    float2 z[4] = { y[0][k1], y[1][k1], y[2][k1], y[3][k1] };
    dft4<S>(z);
    #pragma unroll
    for (int k2 = 0; k2 < 4; ++k2) v[k1 + 8*k2] = z[k2];
  }
}

template<int S>
__device__ __forceinline__ void stage_twiddle32(float2 v[32], float ang){
  float s1,c1,s8,c8;
  __sincosf(ang, &s1, &c1);
  __sincosf(8.f*ang, &s8, &c8);
  float2 w1 = make_float2(c1, s1), w8 = make_float2(c8, s8);
  float2 w16 = cmul(w8, w8), w24 = cmul(w16, w8);
  float2 base[4] = { make_float2(1.f, 0.f), w8, w16, w24 };
  #pragma unroll
  for (int m = 0; m < 4; ++m) {
    float2 wr = base[m];
    if (m > 0) v[8*m] = cmul(v[8*m], wr);
    #pragma unroll
    for (int l = 1; l < 8; ++l) { wr = cmul(wr, w1); v[8*m+l] = cmul(v[8*m+l], wr); }
  }
}

// ========== FWD FUSED: stages LG0 + LG5 through LDS (verified round 7) ==========
__global__ __launch_bounds__(256) void fft_fwd_fused(const float* __restrict__ d1, const float* __restrict__ d2,
                                                     float2* __restrict__ out, int cb, int ch0)
{
  __shared__ float2 lds[256*33];   // 67.6 KB, stride-33 rows
  const int bid = blockIdx.x;
  const int c = bid >> 2, b = bid & 3;
  const int t = threadIdx.x;
  const float* src = (c < cb) ? (d1 + (size_t)(ch0 + c) * NPTS)
                              : (d2 + (size_t)(ch0 + c - cb) * NPTS);
  const float2* src2 = reinterpret_cast<const float2*>(src);

  const int j1 = 8*b + (t & 7) + 32*(t >> 3);
  float2 v[32];
  #pragma unroll
  for (int r = 0; r < 32; ++r) {
    int m = j1 + (r << 10);
    v[r] = (m < NHALF) ? src2[m] : make_float2(0.f, 0.f);
  }
  dft32<-1>(v);
  #pragma unroll
  for (int r = 0; r < 32; ++r) lds[t*33 + r] = v[r];
  __syncthreads();

  const int d = t >> 5, jm = t & 31;
  #pragma unroll
  for (int r = 0; r < 32; ++r) v[r] = lds[(d + 8*r)*33 + jm];
  stage_twiddle32<-1>(v, -(2.0f*PI_F) * (float)jm * (1.0f/1024.0f));
  dft32<-1>(v);
  const int j2 = 256*b + t;
  float2* dst = out + (size_t)c * STR + ((j2 >> 5) << 10) + jm;
  #pragma unroll
  for (int r = 0; r < 32; ++r) dst[(size_t)(r << 5)] = v[r];
}

// ---------- generic Stockham radix-32 pass, Ns = 2^LG ----------
template<int LG, int S>
__global__ __launch_bounds__(256) void fft_pass32(const float2* __restrict__ in, float2* __restrict__ out)
{
  int tid = blockIdx.x*256 + threadIdx.x;
  int c = tid >> 10;
  int j = tid & (NBF32-1);
  const float2* src = in + (size_t)c * STR;
  float2 v[32];
  #pragma unroll
  for (int r = 0; r < 32; ++r) v[r] = src[j + (r << 10)];
  constexpr int NS = 1 << LG;
  int jm = j & (NS - 1);
  if constexpr (LG > 0) {
    float ang = (float)S * (2.0f*PI_F) * (float)jm / (float)(NS*32);
    stage_twiddle32<S>(v, ang);
  }
  dft32<S>(v);
  int idxD = ((j >> LG) << (LG+5)) + jm;
  float2* dst = out + (size_t)c * STR + idxD;
  #pragma unroll
  for (int r = 0; r < 32; ++r) dst[(size_t)(r << LG)] = v[r];
}

// ---------- whitening: round-2 structure + twiddle/taper complex recurrences ----------
__device__ __forceinline__ int padidx(int m){ return m + (m >> 5); }

__global__ __launch_bounds__(1024) void whiten_kernel(float2* __restrict__ buf)
{
  const int ch = blockIdx.x;
  const int t  = threadIdx.x;
  float2* Z = buf + (size_t)ch * STR;
  __shared__ float s[33793];     // 32769 magnitudes, padded every 32
  __shared__ float wsums[16];

  float2 X[33];
  // phase 1: unpack X[k]; twiddle w(k)=e^{-i pi k/32768} via recurrence (step e^{-i pi/32})
  {
    float s0, c0; __sincosf(-PI_F*(float)t*(1.0f/32768.0f), &s0, &c0);
    float2 uw = make_float2(c0, s0);
    const float2 uwstep = make_float2(UC, -US);
    #pragma unroll
    for (int i = 0; i < 33; ++i) {
      int k = i*1024 + t;
      if (i < 32 || t == 0) {
        float2 zk = Z[k & (NFFT-1)];
        float2 zn = Z[(NFFT - k) & (NFFT-1)];
        float2 xe = make_float2(0.5f*(zk.x+zn.x), 0.5f*(zk.y-zn.y));
        float2 xh = make_float2(0.5f*(zk.x-zn.x), 0.5f*(zk.y+zn.y));
        float2 xo = make_float2(xh.y, -xh.x);
        X[i] = cadd(xe, cmul(uw, xo));
        s[padidx(k)] = sqrtf(X[i].x*X[i].x + X[i].y*X[i].y);
      }
      uw = cmul(uw, uwstep);
    }
  }
  __syncthreads();

  // phase 2: block-wide inclusive cumsum of magnitudes (in place in LDS)
  const int base = t*32;
  float sum = 0.f;
  #pragma unroll
  for (int q = 0; q < 32; ++q) sum += s[padidx(base+q)];
  if (t == 1023) sum += s[padidx(32768)];
  const int lane = t & 63, wid = t >> 6;
  float v = sum;
  #pragma unroll
  for (int off = 1; off < 64; off <<= 1) {
    float u = __shfl_up(v, off);
    if (lane >= off) v += u;
  }
  if (lane == 63) wsums[wid] = v;
  __syncthreads();
  float wexcl = 0.f;
  for (int w = 0; w < 16; ++w) wexcl += (w < wid) ? wsums[w] : 0.f;
  float run = wexcl + (v - sum);
  #pragma unroll
  for (int q = 0; q < 32; ++q) {
    int idx = padidx(base+q);
    run += s[idx];
    s[idx] = run;
  }
  if (t == 1023) { int idx = padidx(32768); run += s[idx]; s[idx] = run; }
  __syncthreads();

  // phase 3: box-mean gain + tapers; hi-taper cos^2 via recurrence
  const float a0 = s[padidx(0)];
  const float alast = s[padidx(32768)] - s[padidx(32767)];
  {
    float su, cu; __sincosf(((float)t - 13108.0f)*(PI_F/39320.0f), &su, &cu);
    float2 tu = make_float2(cu, su);
    float tss, tcc; __sincosf(1024.0f*(PI_F/39320.0f), &tss, &tcc);
    const float2 tustep = make_float2(tcc, tss);
    #pragma unroll
    for (int i = 0; i < 33; ++i) {
      int k = i*1024 + t;
      if (i < 32 || t == 0) {
        int hi = k + 327; if (hi > 32768) hi = 32768;
        int lom1 = k - 328;
        float Shi = s[padidx(hi)];
        float Slo = (lom1 >= 0) ? s[padidx(lom1)] : 0.f;
        float lc = (k < 327) ? (float)(327 - k) : 0.f;
        float rc = (k > 32441) ? (float)(k - 32441) : 0.f;
        float smoothed = (lc*a0 + (Shi - Slo) + rc*alast) * (1.0f/655.0f);
        float2 wv;
        if (smoothed > 0.f) {
          float inv = 1.0f / smoothed;
          wv = make_float2(X[i].x*inv, X[i].y*inv);
        } else wv = make_float2(0.f, 0.f);
        float tp = 1.0f;
        if (k < 131)        { float sn = __sinf((float)k * (PI_F/260.0f)); tp = sn*sn; }
        else if (k >= 13108) tp = tu.x*tu.x;
        wv.x *= tp; wv.y *= tp;
        Z[k] = wv;
      }
      tu = cmul(tu, tustep);
    }
  }
}

// ================= CROSS_INV0_PAIR (round-8/12 verified; reads every W bin exactly once) =================
__device__ __forceinline__ float2 pack_zinv(float2 Ck, float2 Cm, float2 pw){
  const float scale = 1.0f/32768.0f;
  float2 xe = make_float2(0.5f*(Ck.x+Cm.x), 0.5f*(Ck.y-Cm.y));
  float2 d  = make_float2(0.5f*(Ck.x-Cm.x), 0.5f*(Ck.y+Cm.y));
  float2 xo = cmul(pw, d);
  return make_float2((xe.x - xo.y)*scale, (xe.y + xo.x)*scale);
}

__global__ __launch_bounds__(256) void cross_inv0_pair(const float2* __restrict__ W,
                                                       float2* __restrict__ out0, int cb)
{
  __shared__ float2 zbs[256*33];   // 67.6 KB zB stash (stride 33)
  const int bid = blockIdx.x;
  const int c = bid >> 1;
  const int t = threadIdx.x;
  const int p = ((bid & 1) << 8) + t;      // pair index 0..511
  const float2* W1 = W + (size_t)c * STR;
  const float2* W2 = W + (size_t)(cb + c) * STR;
  const float scale = 1.0f/32768.0f;
  float2 zA[32];
  float2* zB = zbs + t*33;

  if (p != 0) {
    const int q = 1024 - p;
    float sp, cp; __sincosf(PI_F*(float)p*(1.0f/32768.0f), &sp, &cp);
    float2 pw = make_float2(cp, sp);
    const float2 pstep = make_float2(UC, US);    // e^{+i pi/32}
    #pragma unroll
    for (int r = 0; r < 32; ++r) {
      int m  = p + (r << 10);
      int mm = q + ((31 - r) << 10);             // = 32768 - m
      float2 Ck = conjmul(W1[m],  W2[m]);
      float2 Cm = conjmul(W1[mm], W2[mm]);
      zA[r]    = pack_zinv(Ck, Cm, pw);
      zB[31-r] = pack_zinv(Cm, Ck, make_float2(-pw.x, pw.y));
      pw = cmul(pw, pstep);
    }
  } else {
    {
      float2 Ck = conjmul(W1[0], W2[0]);
      float2 Cm = conjmul(W1[32768], W2[32768]);
      zA[0] = pack_zinv(Ck, Cm, make_float2(1.f, 0.f));
    }
    #pragma unroll
    for (int i = 1; i < 16; ++i) {
      int k = i << 10, km = 32768 - k;
      float2 Ck = conjmul(W1[k],  W2[k]);
      float2 Cm = conjmul(W1[km], W2[km]);
      float sp2, cp2; __sincosf(PI_F*(float)k*(1.0f/32768.0f), &sp2, &cp2);
      zA[i]    = pack_zinv(Ck, Cm, make_float2(cp2, sp2));
      zA[32-i] = pack_zinv(Cm, Ck, make_float2(-cp2, sp2));
    }
    {
      float2 Ck = conjmul(W1[16384], W2[16384]);
      zA[16] = make_float2(Ck.x*scale, -Ck.y*scale);   // Zinv[16384] = conj(C)/N
    }
    #pragma unroll
    for (int i = 0; i < 16; ++i) {
      int k = (i << 10) + 512, km = 32768 - k;
      float2 Ck = conjmul(W1[k],  W2[k]);
      float2 Cm = conjmul(W1[km], W2[km]);
      float sp2, cp2; __sincosf(PI_F*(float)k*(1.0f/32768.0f), &sp2, &cp2);
      zB[i]    = pack_zinv(Ck, Cm, make_float2(cp2, sp2));
      zB[31-i] = pack_zinv(Cm, Ck, make_float2(-cp2, sp2));
    }
  }

  dft32<1>(zA);
  {
    float4* o4 = reinterpret_cast<float4*>(out0 + (size_t)c*STR + (size_t)p*32);
    #pragma unroll
    for (int r = 0; r < 32; r += 2)
      o4[r>>1] = make_float4(zA[r].x, zA[r].y, zA[r+1].x, zA[r+1].y);
  }
  {
    float2 zq[32];
    #pragma unroll
    for (int r = 0; r < 32; ++r) zq[r] = zB[r];
    dft32<1>(zq);
    const int jout = (p == 0) ? 512 : (1024 - p);
    float4* o4 = reinterpret_cast<float4*>(out0 + (size_t)c*STR + (size_t)jout*32);
    #pragma unroll
    for (int r = 0; r < 32; r += 2)
      o4[r>>1] = make_float4(zq[r].x, zq[r].y, zq[r+1].x, zq[r+1].y);
  }
}

// ---------- inverse final pass (Ns=1024, radix-32), fused unpack + roll + slice (verified r7) ----------
__global__ __launch_bounds__(256) void fft_inv_final32(const float2* __restrict__ in, float* __restrict__ out, int ch0)
{
  int tid = blockIdx.x*256 + threadIdx.x;
  int c = tid >> 10;
  int j = tid & (NBF32-1);
  const float2* src = in + (size_t)c * STR;
  float2 v[32];
  #pragma unroll
  for (int r = 0; r < 32; ++r) v[r] = src[j + (r << 10)];
  float ang = (2.0f*PI_F) * (float)j * (1.0f/32768.0f);
  stage_twiddle32<1>(v, ang);
  dft32<1>(v);
  float* o = out + (size_t)(ch0 + c) * XCOR;
  #pragma unroll
  for (int r = 0; r < 32; ++r) {
    int n = j + (r << 10);
    int m = 2*n;
    int j1 = (m <= 29999) ? (m + 29999) : ((m >= 35537) ? (m - 35537) : -1);
    if (j1 >= 0) o[j1] = v[r].x;
    int m2 = m + 1;
    int j2 = (m2 <= 29999) ? (m2 + 29999) : ((m2 >= 35537) ? (m2 - 35537) : -1);
    if (j2 >= 0) o[j2] = v[r].y;
  }
}

__global__ void diag_kernel(float* out, float vv){ if (threadIdx.x==0 && blockIdx.x==0) out[0] = vv; }

extern "C" void kernel_launch(void* const* d_in, const int* in_sizes, int n_in,
                              void* d_out, int out_size, void* d_ws, size_t ws_size,
                              hipStream_t stream)
{
  const float* d1 = (const float*)d_in[0];
  const float* d2 = (const float*)d_in[1];
  float* out = (float*)d_out;

  const size_t bytesPerCh = 2ULL * 2ULL * (size_t)STR * sizeof(float2);
  int CB = (int)(ws_size / bytesPerCh);
  if (CB > NCH) CB = NCH;
  if (CB < 1) { diag_kernel<<<1,1,0,stream>>>(out, (float)ws_size); return; }

  float2* bufA = (float2*)d_ws;
  float2* bufB = bufA + (size_t)2 * CB * STR;

  for (int ch0 = 0; ch0 < NCH; ch0 += CB) {
    int cb = (NCH - ch0 < CB) ? (NCH - ch0) : CB;
    int nch2 = 2*cb;
    dim3 thr(256);

    // forward: fused stages LG0+LG5 (inputs -> A), then LG10 -> natural-order Z (A -> B)
    fft_fwd_fused     <<<dim3(nch2*4), thr, 0, stream>>>(d1, d2, bufA, cb, ch0);
    fft_pass32<10,-1> <<<dim3(nch2*4), thr, 0, stream>>>(bufA, bufB);

    // whiten in place on natural-order Z (B)
    whiten_kernel     <<<dim3(nch2), dim3(1024), 0, stream>>>(bufB);

    // pair-ownership cross-spectrum + irfft pack + inverse stage-0: B -> A
    cross_inv0_pair   <<<dim3(cb*2), thr, 0, stream>>>(bufB, bufA, cb);

    // inverse: middle pass LG=5 (A -> B), final LG=10 fused with roll + slice (B -> out)
    fft_pass32<5,1>   <<<dim3(cb*4), thr, 0, stream>>>(bufA, bufB);
    fft_inv_final32   <<<dim3(cb*4), thr, 0, stream>>>(bufB, out, ch0);
  }
}